// Round 10
// baseline (199.944 us; speedup 1.0000x reference)
//
#include <hip/hip_runtime.h>

#define T 50
#define NB 64
#define NS 512
#define START_TAG 48
#define STOP_TAG 49
#define NCH 16
#define CHL 32
#define NBLK (NB * NCH)   // 1024 one-wave chunk tasks
#define S_E_INT 6

typedef _Float16 f16_t;
typedef _Float16 f16x2 __attribute__((ext_vector_type(2)));
typedef _Float16 f16x8 __attribute__((ext_vector_type(8)));
typedef float    f32x16 __attribute__((ext_vector_type(16)));
typedef unsigned u32;

static constexpr float LOG2E = 1.4426950408889634f;
static constexpr float LN2F  = 0.6931471805599453f;
#define NEG_BIG (-1.0e38f)

__device__ __forceinline__ float fexp2(float x){ return __builtin_amdgcn_exp2f(x); }
__device__ __forceinline__ float flog2(float x){ return __builtin_amdgcn_logf(x); }
__device__ __forceinline__ float bcastf(float v, int l){ return __uint_as_float(__builtin_amdgcn_readlane(__float_as_uint(v), l)); }
__device__ __forceinline__ u32 pkrtz(float a, float b){ return __builtin_bit_cast(u32, __builtin_amdgcn_cvt_pkrtz(a, b)); }
__device__ __forceinline__ f16x2 pack_h2(float a, float b){ return __builtin_bit_cast(f16x2, __builtin_amdgcn_cvt_pkrtz(a, b)); }
__device__ __forceinline__ f16x2 bcast_h2(f16x2 v, int src){ u32 u = __builtin_amdgcn_readlane(__builtin_bit_cast(u32, v), src); return __builtin_bit_cast(f16x2, u); }
__device__ __forceinline__ f16x8 splat8(float s){ u32 u = pkrtz(s, s); uint4 q = make_uint4(u,u,u,u); return __builtin_bit_cast(f16x8, q); }
__device__ __forceinline__ f32x16 zero16(){
    f32x16 z;
    #pragma unroll
    for (int i = 0; i < 16; i++) z[i] = 0.f;
    return z;
}
__device__ __forceinline__ f32x16 mfma32(f16x8 a, uint4 b, f32x16 c){
    return __builtin_amdgcn_mfma_f32_32x32x16_f16(a, __builtin_bit_cast(f16x8, b), c, 0, 0, 0);
}
// d0 = [x.lo | y.lo(from low lanes)] ; d2 = [x.hi(to low lanes) | y.hi]
__device__ __forceinline__ void half_swap(bool hi, u32 x, u32 y, u32 &d0, u32 &d2){
    u32 sy = __shfl_xor(y, 32, 64);
    u32 sx = __shfl_xor(x, 32, 64);
    d0 = hi ? sy : x;
    d2 = hi ? y : sx;
}
__device__ __forceinline__ float wave_max(float m){
    m = fmaxf(m, __shfl_xor(m, 1, 64));
    m = fmaxf(m, __shfl_xor(m, 2, 64));
    m = fmaxf(m, __shfl_xor(m, 4, 64));
    m = fmaxf(m, __shfl_xor(m, 8, 64));
    return fmaxf(fmaxf(bcastf(m, 0), bcastf(m, 16)), fmaxf(bcastf(m, 32), bcastf(m, 48)));
}
__device__ __forceinline__ int exp_of(float g){ return (int)((__float_as_uint(g) >> 23) & 255) - 127; }

// Fused CRF NLL. Phase 1 (all 1024 blocks, 1 wave each): chunk product
// P_c = prod over active t in chunk of (E*D_t), built by LEFT multiplications
// Q <- (D_s E) Q (regrouping E D_1 E D_2 ... = E (D_1 E)(D_2 E)...D_L), with
// 32x32x16 f16 MFMA chained ENTIRELY through registers: the C/D layout
// (lane=col, 16 rows) converts to B-operand layout (lane=col, 8 k per half)
// with 8 cvt_pkrtz + 4 half-wave swaps per 32x32 block. Row-scale ds[m] is
// per-lane-uniform on A (lane=row) -> 1 shfl + pk_mul against constant E
// frags. Exact power-of-2 renorm per step (wave max -> exponent), integer D.
// Phase 2 (first 64 blocks after a device-scope counter barrier; producer
// blocks exit so no deadlock): verified R7 combine + gold + terminal.
__global__ __launch_bounds__(64, 2)
void crf_fused(const float* __restrict__ feats, const int* __restrict__ mask,
               const int* __restrict__ tags, const float* __restrict__ trans,
               f16_t* __restrict__ wsCt, float* __restrict__ wsD,
               u32* __restrict__ ctr, float* __restrict__ out) {
    const int lane = threadIdx.x;
    const int bid  = blockIdx.x;
    const int b    = bid >> 4;          // NCH = 16
    const int c    = bid & 15;
    const int h    = lane >> 5;
    const bool hi  = (h != 0);
    const int n31  = lane & 31;

    // ---- E0 A-frags: Ef[bi][k16][j] = 2^(trans[32bi+n31][16k16+8h+j]*l2e - 6)
    f16x8 Ef[2][4];
    #pragma unroll
    for (int bi = 0; bi < 2; bi++)
      #pragma unroll
      for (int k16 = 0; k16 < 4; k16++) {
        f16x8 v;
        #pragma unroll
        for (int j = 0; j < 8; j++) {
            int row = 32*bi + n31, col = 16*k16 + 8*h + j;
            float x = 0.f;
            if (row < T && col < T) x = fexp2(fmaf(trans[row*T + col], LOG2E, -(float)S_E_INT));
            v[j] = (f16_t)x;
        }
        Ef[bi][k16] = v;
      }

    int tmq = 1 + c*CHL + lane;
    int mv  = (lane < CHL && tmq < NS) ? mask[b*NS + tmq] : 0;
    unsigned long long bal = __ballot(mv != 0);

    uint4 Bf[4][2];
    f32x16 a00 = zero16(), a01 = zero16(), a10 = zero16(), a11 = zero16();
    int D_int = 0, eS = 0;

    if (bal != 0) {
        int s0i = 63 - __clzll(bal); bal &= ~(1ull << s0i);
        const int NM = __popcll(bal) + 1;   // (L-1) scaled mults + 1 leading-E mult

        auto loadf = [&](int s) -> float {
            int t = 1 + c*CHL + s;
            return (lane < T) ? feats[((size_t)b*NS + t)*T + lane] : 0.f;
        };

        float fP = loadf(s0i);
        int sA = bal ? (63 - __clzll(bal)) : -1; if (sA >= 0) bal &= ~(1ull << sA);
        float fA = (sA >= 0) ? loadf(sA) : 0.f;   // f==0 encodes the lead mult (ds=1)
        int sB = bal ? (63 - __clzll(bal)) : -1; if (sB >= 0) bal &= ~(1ull << sB);
        float fB = (sB >= 0) ? loadf(sB) : 0.f;

        // ---- Q := diag(ds_last) as B-frags
        float dsl = fexp2(fP * LOG2E);
        float dsw = __shfl_xor(dsl, 32, 64);
        float dc0 = hi ? dsw : dsl;     // ds[n31]
        float dc1 = hi ? dsl : dsw;     // ds[32+n31]
        u32 db0 = pkrtz(dc0, 0.f) & 0xffffu;
        u32 db1 = pkrtz(dc1, 0.f) & 0xffffu;
        #pragma unroll
        for (int k16 = 0; k16 < 4; k16++)
          #pragma unroll
          for (int bj = 0; bj < 2; bj++) {
            int jeq = 32*bj + n31 - 16*k16 - 8*h;
            u32 dv = (bj ? db1 : db0) << ((jeq & 1) * 16);
            bool in = (jeq >= 0) & (jeq < 8);
            uint4 f;
            f.x = (in && (jeq >> 1) == 0) ? dv : 0u;
            f.y = (in && (jeq >> 1) == 1) ? dv : 0u;
            f.z = (in && (jeq >> 1) == 2) ? dv : 0u;
            f.w = (in && (jeq >> 1) == 3) ? dv : 0u;
            Bf[k16][bj] = f;
          }

        int e2 = exp_of(wave_max(dsl)) + 2;
        e2 = e2 < -20 ? -20 : (e2 > 24 ? 24 : e2);

        for (int i = 0; i < NM; i++) {
            float fc = fA;
            fA = fB;
            int sC = bal ? (63 - __clzll(bal)) : -1; if (sC >= 0) bal &= ~(1ull << sC);
            fB = (sC >= 0) ? loadf(sC) : 0.f;

            // A = (rowscale * descale) ⊙ E   (rowscale per-lane-uniform)
            float dsf = fexp2(fc * LOG2E);
            float dcl = __uint_as_float((u32)(127 - e2) << 23);
            float rsf = dsf * dcl;
            float rsw = __shfl_xor(rsf, 32, 64);
            f16x8 rv0 = splat8(hi ? rsw : rsf);
            f16x8 rv1 = splat8(hi ? rsf : rsw);
            f16x8 A0[4], A1[4];
            #pragma unroll
            for (int k = 0; k < 4; k++) { A0[k] = Ef[0][k] * rv0; A1[k] = Ef[1][k] * rv1; }

            a00 = zero16(); a01 = zero16(); a10 = zero16(); a11 = zero16();
            #pragma unroll
            for (int k = 0; k < 4; k++) {
                a00 = mfma32(A0[k], Bf[k][0], a00);
                a01 = mfma32(A0[k], Bf[k][1], a01);
                a10 = mfma32(A1[k], Bf[k][0], a10);
                a11 = mfma32(A1[k], Bf[k][1], a11);
            }
            D_int += S_E_INT + e2;

            // exact wave max -> next descale exponent (and final store scale)
            float mx = 0.f;
            #pragma unroll
            for (int r = 0; r < 16; r++)
                mx = fmaxf(mx, fmaxf(fmaxf(a00[r], a01[r]), fmaxf(a10[r], a11[r])));
            float g = wave_max(mx);
            eS = exp_of(g);
            e2 = eS + 2; e2 = e2 < -20 ? -20 : (e2 > 24 ? 24 : e2);

            // pack + half-swap: accum (C/D layout) -> B-frags, all in registers
            #define PACKBLK(AC, KA, KB, BJ) { \
                u32 P1 = pkrtz(AC[0], AC[1]),  P2 = pkrtz(AC[2], AC[3]);   \
                u32 Q1 = pkrtz(AC[4], AC[5]),  Q2 = pkrtz(AC[6], AC[7]);   \
                u32 R1 = pkrtz(AC[8], AC[9]),  R2 = pkrtz(AC[10], AC[11]); \
                u32 S1 = pkrtz(AC[12], AC[13]), S2 = pkrtz(AC[14], AC[15]);\
                u32 d0,d2,e0,e2v,g0,g2,h0,h2v;                             \
                half_swap(hi, P1, Q1, d0, d2); half_swap(hi, P2, Q2, e0, e2v); \
                half_swap(hi, R1, S1, g0, g2); half_swap(hi, R2, S2, h0, h2v); \
                Bf[KA][BJ] = make_uint4(d0, e0, d2, e2v);                  \
                Bf[KB][BJ] = make_uint4(g0, h0, g2, h2v);                  \
            }
            PACKBLK(a00, 0, 1, 0)
            PACKBLK(a01, 0, 1, 1)
            PACKBLK(a10, 2, 3, 0)
            PACKBLK(a11, 2, 3, 1)
            #undef PACKBLK
        }

        // ---- store normalized (max in [1,2)) transposed f16 + integer shift
        float sc = __uint_as_float((u32)(127 - eS) << 23);
        f16_t* base = wsCt + (size_t)(b*NCH + c) * 4096;
        #define STOREBLK(AC, BI, BJ) {                                       \
            int col = 32*(BJ) + n31;                                         \
            _Pragma("unroll")                                                \
            for (int g4 = 0; g4 < 4; g4++) {                                 \
                u32 X = pkrtz(AC[4*g4+0]*sc, AC[4*g4+1]*sc);                 \
                u32 Y = pkrtz(AC[4*g4+2]*sc, AC[4*g4+3]*sc);                 \
                int row0 = 32*(BI) + 8*g4 + 4*h;                             \
                *(uint2*)(base + col*64 + row0) = make_uint2(X, Y);          \
            }                                                                \
        }
        STOREBLK(a00, 0, 0)
        STOREBLK(a01, 0, 1)
        STOREBLK(a10, 1, 0)
        STOREBLK(a11, 1, 1)
        #undef STOREBLK
        if (lane == 0) wsD[b*NCH + c] = (float)(D_int + eS);
    } else {
        // no active steps: chunk matrix = I
        f16_t* base = wsCt + (size_t)(b*NCH + c) * 4096;
        #pragma unroll
        for (int bj = 0; bj < 2; bj++) {
            int col = 32*bj + n31;
            #pragma unroll
            for (int bi = 0; bi < 2; bi++)
              #pragma unroll
              for (int g4 = 0; g4 < 4; g4++) {
                int row0 = 32*bi + 8*g4 + 4*h;
                u32 X = pkrtz(row0+0 == col ? 1.f : 0.f, row0+1 == col ? 1.f : 0.f);
                u32 Y = pkrtz(row0+2 == col ? 1.f : 0.f, row0+3 == col ? 1.f : 0.f);
                *(uint2*)(base + col*64 + row0) = make_uint2(X, Y);
              }
        }
        if (lane == 0) wsD[b*NCH + c] = 0.f;
    }

    // ================= device-scope barrier ================================
    __threadfence();
    if (lane == 0) __hip_atomic_fetch_add(ctr, 1u, __ATOMIC_ACQ_REL, __HIP_MEMORY_SCOPE_AGENT);
    if (bid >= NB) return;              // producers exit -> no deadlock

    // ================= phase 2: combine (one wave per batch) ===============
    const int bb = bid;

    // gold score (independent of workspace -> overlap with the wait)
    float gsum = 0.f;
    int   lcnt = 0;
    for (int s = lane; s < NS; s += 64) {
        int   m  = mask[bb * NS + s];
        int   tg = tags[bb * NS + s];
        int   pv = (s == 0) ? START_TAG : tags[bb * NS + s - 1];
        float e  = feats[((size_t)bb * NS + s) * T + tg];
        float tr = trans[pv * T + tg];
        if (m) { gsum += e + tr; lcnt += 1; }
    }
    #pragma unroll
    for (int off = 32; off > 0; off >>= 1) {
        gsum += __shfl_down(gsum, off, 64);
        lcnt += __shfl_down(lcnt, off, 64);
    }
    float goldb = 0.f;
    if (lane == 0) goldb = gsum + trans[tags[bb * NS + lcnt - 1] * T + STOP_TAG];

    float part = (lane < T)
        ? (feats[(size_t)bb * NS * T + lane] + trans[START_TAG * T + lane]) * LOG2E
        : NEG_BIG;

    while (__hip_atomic_load(ctr, __ATOMIC_ACQUIRE, __HIP_MEMORY_SCOPE_AGENT) < (u32)NBLK)
        __builtin_amdgcn_s_sleep(8);

    float Dv[NCH];
    #pragma unroll
    for (int cc = 0; cc < NCH; cc++) Dv[cc] = wsD[bb*NCH + cc];

    int cur[32], nxt[32];
    {
        const f16_t* src = wsCt + (size_t)bb * NCH * 4096 + lane * 64;
        #pragma unroll
        for (int kk = 0; kk < 8; kk++) *(int4*)&cur[4*kk] = ((const int4*)src)[kk];
    }

    #pragma unroll
    for (int cc = 0; cc < NCH; cc++) {
        if (cc + 1 < NCH) {
            const f16_t* src = wsCt + (size_t)(bb*NCH + cc + 1) * 4096 + lane * 64;
            #pragma unroll
            for (int kk = 0; kk < 8; kk++) *(int4*)&nxt[4*kk] = ((const int4*)src)[kk];
        }
        float sft = part;
        #pragma unroll
        for (int off = 32; off > 0; off >>= 1) sft = fmaxf(sft, __shfl_xor(sft, off, 64));
        float ex  = fexp2(part - sft);
        float exo = __shfl_xor(ex, 1, 64);
        f16x2 pk  = pack_h2(ex, exo);

        float A0 = 0.f, A1 = 0.f, A2 = 0.f, A3 = 0.f;
        #pragma unroll
        for (int p = 0; p < 25; p += 4) {
            A0 = __builtin_amdgcn_fdot2(bcast_h2(pk, 2*p), __builtin_bit_cast(f16x2, cur[p]), A0, false);
            if (p + 1 < 25) A1 = __builtin_amdgcn_fdot2(bcast_h2(pk, 2*(p+1)), __builtin_bit_cast(f16x2, cur[p+1]), A1, false);
            if (p + 2 < 25) A2 = __builtin_amdgcn_fdot2(bcast_h2(pk, 2*(p+2)), __builtin_bit_cast(f16x2, cur[p+2]), A2, false);
            if (p + 3 < 25) A3 = __builtin_amdgcn_fdot2(bcast_h2(pk, 2*(p+3)), __builtin_bit_cast(f16x2, cur[p+3]), A3, false);
        }
        part = sft + Dv[cc] + flog2((A0 + A1) + (A2 + A3));

        if (cc + 1 < NCH) {
            #pragma unroll
            for (int kk = 0; kk < 32; kk++) cur[kk] = nxt[kk];
        }
    }

    float v = (lane < T) ? part + trans[lane * T + STOP_TAG] * LOG2E : NEG_BIG;
    float mx = v;
    #pragma unroll
    for (int off = 32; off > 0; off >>= 1) mx = fmaxf(mx, __shfl_xor(mx, off, 64));
    float ee = (lane < T) ? fexp2(v - mx) : 0.f;
    #pragma unroll
    for (int off = 32; off > 0; off >>= 1) ee += __shfl_xor(ee, off, 64);
    if (lane == 0) {
        float fwd = (mx + flog2(ee)) * LN2F;
        atomicAdd(out, fwd - goldb);
    }
}

extern "C" void kernel_launch(void* const* d_in, const int* in_sizes, int n_in,
                              void* d_out, int out_size, void* d_ws, size_t ws_size,
                              hipStream_t stream) {
    const float* feats = (const float*)d_in[0];
    const int*   mask  = (const int*)d_in[1];
    const int*   tags  = (const int*)d_in[2];
    const float* trans = (const float*)d_in[3];
    float* out = (float*)d_out;

    size_t offD = (size_t)NB * NCH * 4096 * sizeof(f16_t);   // 8 MB
    f16_t* wsCt = (f16_t*)d_ws;
    float* wsD  = (float*)((char*)d_ws + offD);
    u32*   ctr  = (u32*)((char*)d_ws + offD + (size_t)NB * NCH * sizeof(float));

    (void)hipMemsetAsync(out, 0, sizeof(float) * out_size, stream);
    (void)hipMemsetAsync(ctr, 0, sizeof(u32), stream);
    crf_fused<<<NBLK, 64, 0, stream>>>(feats, mask, tags, trans, wsCt, wsD, ctr, out);
}

// Round 11
// 191.379 us; speedup vs baseline: 1.0448x; 1.0448x over previous
//
#include <hip/hip_runtime.h>

#define T 50
#define NB 64
#define NS 512
#define START_TAG 48
#define STOP_TAG 49
#define NCH 16
#define CHL 32
#define NBLK (NB * NCH)   // 1024 one-wave chunk tasks
#define S_E_INT 6

typedef _Float16 f16_t;
typedef _Float16 f16x2 __attribute__((ext_vector_type(2)));
typedef _Float16 f16x8 __attribute__((ext_vector_type(8)));
typedef float    f32x16 __attribute__((ext_vector_type(16)));
typedef unsigned u32;

static constexpr float LOG2E = 1.4426950408889634f;
static constexpr float LN2F  = 0.6931471805599453f;
#define NEG_BIG (-1.0e38f)

__device__ __forceinline__ float fexp2(float x){ return __builtin_amdgcn_exp2f(x); }
__device__ __forceinline__ float flog2(float x){ return __builtin_amdgcn_logf(x); }
__device__ __forceinline__ float bcastf(float v, int l){ return __uint_as_float(__builtin_amdgcn_readlane(__float_as_uint(v), l)); }
__device__ __forceinline__ u32 pkrtz(float a, float b){ return __builtin_bit_cast(u32, __builtin_amdgcn_cvt_pkrtz(a, b)); }
__device__ __forceinline__ f16x2 pack_h2(float a, float b){ return __builtin_bit_cast(f16x2, __builtin_amdgcn_cvt_pkrtz(a, b)); }
__device__ __forceinline__ f16x2 bcast_h2(f16x2 v, int src){ u32 u = __builtin_amdgcn_readlane(__builtin_bit_cast(u32, v), src); return __builtin_bit_cast(f16x2, u); }
__device__ __forceinline__ f16x8 splat8(float s){ u32 u = pkrtz(s, s); uint4 q = make_uint4(u,u,u,u); return __builtin_bit_cast(f16x8, q); }
__device__ __forceinline__ f32x16 zero16(){
    f32x16 z;
    #pragma unroll
    for (int i = 0; i < 16; i++) z[i] = 0.f;
    return z;
}
__device__ __forceinline__ f32x16 mfma32(f16x8 a, uint4 b, f32x16 c){
    return __builtin_amdgcn_mfma_f32_32x32x16_f16(a, __builtin_bit_cast(f16x8, b), c, 0, 0, 0);
}
// Single-shfl half swap (R10 used two ds_permutes; each lane only keeps one
// half of each, so sending hi?x:y and receiving the partner's value delivers
// exactly the needed piece):
//   d0 = [x.lo | y.lo(from low lanes)] ; d2 = [x.hi(to low lanes) | y.hi]
__device__ __forceinline__ void half_swap(bool hi, u32 x, u32 y, u32 &d0, u32 &d2){
    u32 sw = __shfl_xor(hi ? x : y, 32, 64);
    d0 = hi ? sw : x;
    d2 = hi ? y : sw;
}
__device__ __forceinline__ float wave_max(float m){
    m = fmaxf(m, __shfl_xor(m, 1, 64));
    m = fmaxf(m, __shfl_xor(m, 2, 64));
    m = fmaxf(m, __shfl_xor(m, 4, 64));
    m = fmaxf(m, __shfl_xor(m, 8, 64));
    return fmaxf(fmaxf(bcastf(m, 0), bcastf(m, 16)), fmaxf(bcastf(m, 32), bcastf(m, 48)));
}
__device__ __forceinline__ int exp_of(float g){ return (int)((__float_as_uint(g) >> 23) & 255) - 127; }

// Fused CRF NLL. Phase 1 (1024 blocks, 1 wave each): chunk product via
// register-chained 32x32x16 f16 MFMA (see R9/R10 comments). launch_bounds
// (64,1): the 1024-wave grid occupies exactly 1 wave/SIMD, so the full
// 512-reg unified budget is available -> accumulators/fragments stay in
// architectural VGPRs (R10's (64,2) cap forced AGPR shuffle traffic, 76
// VGPRs reported). Phase 2 (first 64 blocks after device-scope counter
// barrier; producers exit so no deadlock): verified combine + gold.
__global__ __launch_bounds__(64, 1)
void crf_fused(const float* __restrict__ feats, const int* __restrict__ mask,
               const int* __restrict__ tags, const float* __restrict__ trans,
               f16_t* __restrict__ wsCt, float* __restrict__ wsD,
               u32* __restrict__ ctr, float* __restrict__ out) {
    const int lane = threadIdx.x;
    const int bid  = blockIdx.x;
    const int b    = bid >> 4;          // NCH = 16
    const int c    = bid & 15;
    const int h    = lane >> 5;
    const bool hi  = (h != 0);
    const int n31  = lane & 31;

    // ---- E0 A-frags: Ef[bi][k16][j] = 2^(trans[32bi+n31][16k16+8h+j]*l2e - 6)
    f16x8 Ef[2][4];
    #pragma unroll
    for (int bi = 0; bi < 2; bi++)
      #pragma unroll
      for (int k16 = 0; k16 < 4; k16++) {
        f16x8 v;
        #pragma unroll
        for (int j = 0; j < 8; j++) {
            int row = 32*bi + n31, col = 16*k16 + 8*h + j;
            float x = 0.f;
            if (row < T && col < T) x = fexp2(fmaf(trans[row*T + col], LOG2E, -(float)S_E_INT));
            v[j] = (f16_t)x;
        }
        Ef[bi][k16] = v;
      }

    int tmq = 1 + c*CHL + lane;
    int mv  = (lane < CHL && tmq < NS) ? mask[b*NS + tmq] : 0;
    unsigned long long bal = __ballot(mv != 0);

    uint4 Bf[4][2];
    f32x16 a00 = zero16(), a01 = zero16(), a10 = zero16(), a11 = zero16();
    int D_int = 0, eS = 0;

    if (bal != 0) {
        int s0i = 63 - __clzll(bal); bal &= ~(1ull << s0i);
        const int NM = __popcll(bal) + 1;   // (L-1) scaled mults + 1 leading-E mult

        auto loadf = [&](int s) -> float {
            int t = 1 + c*CHL + s;
            return (lane < T) ? feats[((size_t)b*NS + t)*T + lane] : 0.f;
        };

        float fP = loadf(s0i);
        int sA = bal ? (63 - __clzll(bal)) : -1; if (sA >= 0) bal &= ~(1ull << sA);
        float fA = (sA >= 0) ? loadf(sA) : 0.f;   // f==0 encodes the lead mult (ds=1)
        int sB = bal ? (63 - __clzll(bal)) : -1; if (sB >= 0) bal &= ~(1ull << sB);
        float fB = (sB >= 0) ? loadf(sB) : 0.f;

        // ---- Q := diag(ds_last) as B-frags
        float dsl = fexp2(fP * LOG2E);
        float dsw = __shfl_xor(dsl, 32, 64);
        float dc0 = hi ? dsw : dsl;     // ds[n31]
        float dc1 = hi ? dsl : dsw;     // ds[32+n31]
        u32 db0 = pkrtz(dc0, 0.f) & 0xffffu;
        u32 db1 = pkrtz(dc1, 0.f) & 0xffffu;
        #pragma unroll
        for (int k16 = 0; k16 < 4; k16++)
          #pragma unroll
          for (int bj = 0; bj < 2; bj++) {
            int jeq = 32*bj + n31 - 16*k16 - 8*h;
            u32 dv = (bj ? db1 : db0) << ((jeq & 1) * 16);
            bool in = (jeq >= 0) & (jeq < 8);
            uint4 f;
            f.x = (in && (jeq >> 1) == 0) ? dv : 0u;
            f.y = (in && (jeq >> 1) == 1) ? dv : 0u;
            f.z = (in && (jeq >> 1) == 2) ? dv : 0u;
            f.w = (in && (jeq >> 1) == 3) ? dv : 0u;
            Bf[k16][bj] = f;
          }

        int e2 = exp_of(wave_max(dsl)) + 2;
        e2 = e2 < -20 ? -20 : (e2 > 24 ? 24 : e2);

        for (int i = 0; i < NM; i++) {
            float fc = fA;
            fA = fB;
            int sC = bal ? (63 - __clzll(bal)) : -1; if (sC >= 0) bal &= ~(1ull << sC);
            fB = (sC >= 0) ? loadf(sC) : 0.f;

            // A = (rowscale * descale) ⊙ E   (rowscale per-lane-uniform)
            float dsf = fexp2(fc * LOG2E);
            float dcl = __uint_as_float((u32)(127 - e2) << 23);
            float rsf = dsf * dcl;
            float rsw = __shfl_xor(rsf, 32, 64);
            f16x8 rv0 = splat8(hi ? rsw : rsf);
            f16x8 rv1 = splat8(hi ? rsf : rsw);
            f16x8 A0[4], A1[4];
            #pragma unroll
            for (int k = 0; k < 4; k++) { A0[k] = Ef[0][k] * rv0; A1[k] = Ef[1][k] * rv1; }

            a00 = zero16(); a01 = zero16(); a10 = zero16(); a11 = zero16();
            #pragma unroll
            for (int k = 0; k < 4; k++) {
                a00 = mfma32(A0[k], Bf[k][0], a00);
                a01 = mfma32(A0[k], Bf[k][1], a01);
                a10 = mfma32(A1[k], Bf[k][0], a10);
                a11 = mfma32(A1[k], Bf[k][1], a11);
            }
            D_int += S_E_INT + e2;

            // exact wave max -> next descale exponent (loop-carried, runs in
            // parallel with the pack path below)
            float mx = 0.f;
            #pragma unroll
            for (int r = 0; r < 16; r++)
                mx = fmaxf(mx, fmaxf(fmaxf(a00[r], a01[r]), fmaxf(a10[r], a11[r])));
            float g = wave_max(mx);
            eS = exp_of(g);
            e2 = eS + 2; e2 = e2 < -20 ? -20 : (e2 > 24 ? 24 : e2);

            // pack + half-swap: accum (C/D layout) -> B-frags, all in registers
            #define PACKBLK(AC, KA, KB, BJ) { \
                u32 P1 = pkrtz(AC[0], AC[1]),  P2 = pkrtz(AC[2], AC[3]);   \
                u32 Q1 = pkrtz(AC[4], AC[5]),  Q2 = pkrtz(AC[6], AC[7]);   \
                u32 R1 = pkrtz(AC[8], AC[9]),  R2 = pkrtz(AC[10], AC[11]); \
                u32 S1 = pkrtz(AC[12], AC[13]), S2 = pkrtz(AC[14], AC[15]);\
                u32 d0,d2,e0,e2v,g0,g2,h0,h2v;                             \
                half_swap(hi, P1, Q1, d0, d2); half_swap(hi, P2, Q2, e0, e2v); \
                half_swap(hi, R1, S1, g0, g2); half_swap(hi, R2, S2, h0, h2v); \
                Bf[KA][BJ] = make_uint4(d0, e0, d2, e2v);                  \
                Bf[KB][BJ] = make_uint4(g0, h0, g2, h2v);                  \
            }
            PACKBLK(a00, 0, 1, 0)
            PACKBLK(a01, 0, 1, 1)
            PACKBLK(a10, 2, 3, 0)
            PACKBLK(a11, 2, 3, 1)
            #undef PACKBLK
        }

        // ---- store normalized (max in [1,2)) transposed f16 + integer shift
        float sc = __uint_as_float((u32)(127 - eS) << 23);
        f16_t* base = wsCt + (size_t)(b*NCH + c) * 4096;
        #define STOREBLK(AC, BI, BJ) {                                       \
            int col = 32*(BJ) + n31;                                         \
            _Pragma("unroll")                                                \
            for (int g4 = 0; g4 < 4; g4++) {                                 \
                u32 X = pkrtz(AC[4*g4+0]*sc, AC[4*g4+1]*sc);                 \
                u32 Y = pkrtz(AC[4*g4+2]*sc, AC[4*g4+3]*sc);                 \
                int row0 = 32*(BI) + 8*g4 + 4*h;                             \
                *(uint2*)(base + col*64 + row0) = make_uint2(X, Y);          \
            }                                                                \
        }
        STOREBLK(a00, 0, 0)
        STOREBLK(a01, 0, 1)
        STOREBLK(a10, 1, 0)
        STOREBLK(a11, 1, 1)
        #undef STOREBLK
        if (lane == 0) wsD[b*NCH + c] = (float)(D_int + eS);
    } else {
        // no active steps: chunk matrix = I
        f16_t* base = wsCt + (size_t)(b*NCH + c) * 4096;
        #pragma unroll
        for (int bj = 0; bj < 2; bj++) {
            int col = 32*bj + n31;
            #pragma unroll
            for (int bi = 0; bi < 2; bi++)
              #pragma unroll
              for (int g4 = 0; g4 < 4; g4++) {
                int row0 = 32*bi + 8*g4 + 4*h;
                u32 X = pkrtz(row0+0 == col ? 1.f : 0.f, row0+1 == col ? 1.f : 0.f);
                u32 Y = pkrtz(row0+2 == col ? 1.f : 0.f, row0+3 == col ? 1.f : 0.f);
                *(uint2*)(base + col*64 + row0) = make_uint2(X, Y);
              }
        }
        if (lane == 0) wsD[b*NCH + c] = 0.f;
    }

    // ================= device-scope barrier ================================
    __threadfence();
    if (lane == 0) __hip_atomic_fetch_add(ctr, 1u, __ATOMIC_ACQ_REL, __HIP_MEMORY_SCOPE_AGENT);
    if (bid >= NB) return;              // producers exit -> no deadlock

    // ================= phase 2: combine (one wave per batch) ===============
    const int bb = bid;

    // gold score (independent of workspace -> overlap with the wait)
    float gsum = 0.f;
    int   lcnt = 0;
    for (int s = lane; s < NS; s += 64) {
        int   m  = mask[bb * NS + s];
        int   tg = tags[bb * NS + s];
        int   pv = (s == 0) ? START_TAG : tags[bb * NS + s - 1];
        float e  = feats[((size_t)bb * NS + s) * T + tg];
        float tr = trans[pv * T + tg];
        if (m) { gsum += e + tr; lcnt += 1; }
    }
    #pragma unroll
    for (int off = 32; off > 0; off >>= 1) {
        gsum += __shfl_down(gsum, off, 64);
        lcnt += __shfl_down(lcnt, off, 64);
    }
    float goldb = 0.f;
    if (lane == 0) goldb = gsum + trans[tags[bb * NS + lcnt - 1] * T + STOP_TAG];

    float part = (lane < T)
        ? (feats[(size_t)bb * NS * T + lane] + trans[START_TAG * T + lane]) * LOG2E
        : NEG_BIG;

    while (__hip_atomic_load(ctr, __ATOMIC_ACQUIRE, __HIP_MEMORY_SCOPE_AGENT) < (u32)NBLK)
        __builtin_amdgcn_s_sleep(8);

    float Dv[NCH];
    #pragma unroll
    for (int cc = 0; cc < NCH; cc++) Dv[cc] = wsD[bb*NCH + cc];

    int cur[32], nxt[32];
    {
        const f16_t* src = wsCt + (size_t)bb * NCH * 4096 + lane * 64;
        #pragma unroll
        for (int kk = 0; kk < 8; kk++) *(int4*)&cur[4*kk] = ((const int4*)src)[kk];
    }

    #pragma unroll
    for (int cc = 0; cc < NCH; cc++) {
        if (cc + 1 < NCH) {
            const f16_t* src = wsCt + (size_t)(bb*NCH + cc + 1) * 4096 + lane * 64;
            #pragma unroll
            for (int kk = 0; kk < 8; kk++) *(int4*)&nxt[4*kk] = ((const int4*)src)[kk];
        }
        float sft = part;
        #pragma unroll
        for (int off = 32; off > 0; off >>= 1) sft = fmaxf(sft, __shfl_xor(sft, off, 64));
        float ex  = fexp2(part - sft);
        float exo = __shfl_xor(ex, 1, 64);
        f16x2 pk  = pack_h2(ex, exo);

        float A0 = 0.f, A1 = 0.f, A2 = 0.f, A3 = 0.f;
        #pragma unroll
        for (int p = 0; p < 25; p += 4) {
            A0 = __builtin_amdgcn_fdot2(bcast_h2(pk, 2*p), __builtin_bit_cast(f16x2, cur[p]), A0, false);
            if (p + 1 < 25) A1 = __builtin_amdgcn_fdot2(bcast_h2(pk, 2*(p+1)), __builtin_bit_cast(f16x2, cur[p+1]), A1, false);
            if (p + 2 < 25) A2 = __builtin_amdgcn_fdot2(bcast_h2(pk, 2*(p+2)), __builtin_bit_cast(f16x2, cur[p+2]), A2, false);
            if (p + 3 < 25) A3 = __builtin_amdgcn_fdot2(bcast_h2(pk, 2*(p+3)), __builtin_bit_cast(f16x2, cur[p+3]), A3, false);
        }
        part = sft + Dv[cc] + flog2((A0 + A1) + (A2 + A3));

        if (cc + 1 < NCH) {
            #pragma unroll
            for (int kk = 0; kk < 32; kk++) cur[kk] = nxt[kk];
        }
    }

    float v = (lane < T) ? part + trans[lane * T + STOP_TAG] * LOG2E : NEG_BIG;
    float mx = v;
    #pragma unroll
    for (int off = 32; off > 0; off >>= 1) mx = fmaxf(mx, __shfl_xor(mx, off, 64));
    float ee = (lane < T) ? fexp2(v - mx) : 0.f;
    #pragma unroll
    for (int off = 32; off > 0; off >>= 1) ee += __shfl_xor(ee, off, 64);
    if (lane == 0) {
        float fwd = (mx + flog2(ee)) * LN2F;
        atomicAdd(out, fwd - goldb);
    }
}

extern "C" void kernel_launch(void* const* d_in, const int* in_sizes, int n_in,
                              void* d_out, int out_size, void* d_ws, size_t ws_size,
                              hipStream_t stream) {
    const float* feats = (const float*)d_in[0];
    const int*   mask  = (const int*)d_in[1];
    const int*   tags  = (const int*)d_in[2];
    const float* trans = (const float*)d_in[3];
    float* out = (float*)d_out;

    size_t offD = (size_t)NB * NCH * 4096 * sizeof(f16_t);   // 8 MB
    f16_t* wsCt = (f16_t*)d_ws;
    float* wsD  = (float*)((char*)d_ws + offD);
    u32*   ctr  = (u32*)((char*)d_ws + offD + (size_t)NB * NCH * sizeof(float));

    (void)hipMemsetAsync(out, 0, sizeof(float) * out_size, stream);
    (void)hipMemsetAsync(ctr, 0, sizeof(u32), stream);
    crf_fused<<<NBLK, 64, 0, stream>>>(feats, mask, tags, trans, wsCt, wsD, ctr, out);
}